// Round 11
// baseline (436.873 us; speedup 1.0000x reference)
//
#include <hip/hip_runtime.h>
#include <stdint.h>

// ---------- types ----------
using s8v  = __attribute__((ext_vector_type(8))) short;    // 8 bf16 (A/B frag)
using f4   = __attribute__((ext_vector_type(4))) float;    // C/D frag
using i8v  = __attribute__((ext_vector_type(8))) int;      // 32B fp8 frag (MX K=128)
using u32x4 = __attribute__((ext_vector_type(4))) uint32_t;
using u32x2 = __attribute__((ext_vector_type(2))) uint32_t;
using vf4  = __attribute__((ext_vector_type(4))) float;
using i4v  = __attribute__((ext_vector_type(4))) int;

typedef unsigned short ushortT;

#define LOG2E 1.4426950408889634f

// bf16 round-to-nearest-even
static __device__ __forceinline__ uint32_t bfr16(float f) {
  union { float f; uint32_t u; } v; v.f = f;
  return (v.u + 0x7FFFu + ((v.u >> 16) & 1u)) >> 16;
}
static __device__ __forceinline__ uint32_t pk2(float lo, float hi) {
  return (bfr16(hi) << 16) | (bfr16(lo) & 0xFFFFu);
}
// pack 4 f32 -> 4 fp8 e4m3 bytes (saturating RNE)
static __device__ __forceinline__ uint32_t pk4fp8(float a, float b, float cc, float d) {
  int w = __builtin_amdgcn_cvt_pk_fp8_f32(a, b, 0, false);    // bytes 0,1
  w = __builtin_amdgcn_cvt_pk_fp8_f32(cc, d, w, true);        // bytes 2,3
  return (uint32_t)w;
}
// native 2^x (single v_exp_f32 — exp2f() is a slow libm call, R9 lesson)
static __device__ __forceinline__ float ex2(float x) {
#if __has_builtin(__builtin_amdgcn_exp2f)
  return __builtin_amdgcn_exp2f(x);
#else
  float r; asm("v_exp_f32 %0, %1" : "=v"(r) : "v"(x)); return r;
#endif
}
// async global->LDS, 16B per lane
static __device__ __forceinline__ void gl16(const void* g, void* l) {
  __builtin_amdgcn_global_load_lds((const __attribute__((address_space(1))) uint32_t*)g,
                                   (__attribute__((address_space(3))) uint32_t*)l, 16, 0, 0);
}

#define MFMA_BF16(A, B, C) __builtin_amdgcn_mfma_f32_16x16x32_bf16((A), (B), (C), 0, 0, 0)
// MX-scaled fp8 K=128, unit scales (E8M0 0x7F = 2^0) in every byte, opsel 0.
#define MFMA_MX(A, B, C) \
  __builtin_amdgcn_mfma_scale_f32_16x16x128_f8f6f4((A), (B), (C), 0, 0, \
                                                   0, 0x7F7F7F7F, 0, 0x7F7F7F7F)

// ---------------------------------------------------------------------------
// Kernel X: x fp32 -> xb bf16 (row-major), one pass.  xb lives in d_out
// (64MB >= 32MB; kproj consumes it before kattn overwrites d_out).
// ---------------------------------------------------------------------------
__global__ __launch_bounds__(256) void kxcvt(const float* __restrict__ x,
                                             ushortT* __restrict__ xb) {
  const size_t stride = (size_t)2048 * 256 * 8;
  size_t idx = ((size_t)blockIdx.x * 256 + threadIdx.x) * 8;
#pragma unroll
  for (int i = 0; i < 4; ++i) {
    vf4 a = *(const vf4*)(x + idx);
    vf4 b = *(const vf4*)(x + idx + 4);
    u32x4 o = { pk2(a[0], a[1]), pk2(a[2], a[3]),
                pk2(b[0], b[1]), pk2(b[2], b[3]) };
    *(u32x4*)(xb + idx) = o;
    idx += stride;
  }
}

// ---------------------------------------------------------------------------
// Kernel 0: weights -> bf16, transposed: Wt[640][512]
// ---------------------------------------------------------------------------
__global__ __launch_bounds__(64) void kprep(const float* __restrict__ Wg,
                                            const float* __restrict__ Wf,
                                            const float* __restrict__ Wh,
                                            ushortT* __restrict__ Wt) {
  const int cIdx = blockIdx.x;     // 0..639
  const int t = threadIdx.x;       // 64
  const float* src; int co, ldc;
  if (cIdx < 64)       { src = Wg; co = cIdx;       ldc = 64;  }
  else if (cIdx < 128) { src = Wf; co = cIdx - 64;  ldc = 64;  }
  else                 { src = Wh; co = cIdx - 128; ldc = 512; }
#pragma unroll
  for (int kk = 0; kk < 8; ++kk) {
    int k = kk * 64 + t;
    Wt[(size_t)cIdx * 512 + k] = (ushortT)bfr16(src[(size_t)k * ldc + co]);
  }
}

// ---------------------------------------------------------------------------
// Kernel 1: projection GEMM, 128x128 tile; BOTH operands gl16-staged from
// bf16 (A from xb — no fp32 re-read, no cvt VALU).
// ---------------------------------------------------------------------------
__global__ __launch_bounds__(256) void kproj(const ushortT* __restrict__ xb,
                                             const ushortT* __restrict__ Wt,
                                             const float* __restrict__ bg,
                                             const float* __restrict__ bfv,
                                             const float* __restrict__ bh,
                                             ushortT* __restrict__ Q,
                                             ushortT* __restrict__ K,
                                             uint8_t* __restrict__ V8) {
  __shared__ ushortT Al[128 * 64];   // 16KB [row][k], chunk16 ^= row&7
  __shared__ ushortT Bl[128 * 64];   // 16KB [col][k], chunk16 ^= col&7

  const int tid = threadIdx.x;
  const int w = tid >> 6, l = tid & 63, h = l >> 4, c = l & 15;
  const int wr = w >> 1, wc = w & 1;           // 2x2 wave grid
  const int ct = blockIdx.x, rt = blockIdx.y;
  const int row0 = rt * 128;

  f4 acc[4][4];
#pragma unroll
  for (int m = 0; m < 4; ++m)
#pragma unroll
    for (int n = 0; n < 4; ++n) acc[m][n] = (f4){0.f, 0.f, 0.f, 0.f};

  for (int kk = 0; kk < 8; ++kk) {
    const int k0 = kk * 64;
    // ---- stage A via gl16: 4 per thread (source pre-swizzled, dest linear)
#pragma unroll
    for (int i = 0; i < 4; ++i) {
      const int ch = i * 256 + tid;              // LDS 16B-chunk index
      const int row = ch >> 3, kc = ch & 7;
      const ushortT* src = xb + (size_t)(row0 + row) * 512 + k0 +
                           8 * (kc ^ (row & 7));
      gl16(src, (char*)Al + ch * 16);
    }
    // ---- stage B: 4 gl16 per wave (source pre-swizzled, dest linear)
#pragma unroll
    for (int i = 0; i < 4; ++i) {
      const int col = w * 32 + i * 8 + (l >> 3);
      const ushortT* src = Wt + (size_t)(ct * 128 + col) * 512 + k0 +
                           8 * ((l & 7) ^ (l >> 3));
      gl16(src, (char*)Bl + (w * 4 + i) * 1024);
    }
    __syncthreads();
    // ---- MFMA: wave (wr,wc) owns rows wr*64.., cols wc*64..
#pragma unroll
    for (int ks = 0; ks < 2; ++ks) {
      s8v a[4], b[4];
#pragma unroll
      for (int m = 0; m < 4; ++m)
        a[m] = *(const s8v*)((char*)Al + (size_t)(wr * 64 + m * 16 + c) * 128 +
                             (((ks * 4 + h) ^ (c & 7)) * 16));
#pragma unroll
      for (int n = 0; n < 4; ++n)
        b[n] = *(const s8v*)((char*)Bl + (size_t)(wc * 64 + n * 16 + c) * 128 +
                             (((ks * 4 + h) ^ (c & 7)) * 16));
#pragma unroll
      for (int m = 0; m < 4; ++m)
#pragma unroll
        for (int n = 0; n < 4; ++n)
          acc[m][n] = MFMA_BF16(a[m], b[n], acc[m][n]);
    }
    __syncthreads();
  }

  // ---- epilogue: route by global column
  if (ct == 0) {
    ushortT* dst = (wc == 0) ? Q : K;
    const float* bias = (wc == 0) ? bg : bfv;
    const float scl = (wc == 0) ? LOG2E : 1.0f;
#pragma unroll
    for (int n = 0; n < 4; ++n) {
      const int col = n * 16 + c;
      const float bv = bias[col];
#pragma unroll
      for (int m = 0; m < 4; ++m) {
        const int grow = row0 + wr * 64 + m * 16 + h * 4;
#pragma unroll
        for (int r = 0; r < 4; ++r)
          dst[(size_t)(grow + r) * 64 + col] = (ushortT)bfr16((acc[m][n][r] + bv) * scl);
      }
    }
  } else {
    const int b = row0 >> 12;
#pragma unroll
    for (int n = 0; n < 4; ++n) {
      const int vcol = ct * 128 + wc * 64 + n * 16 + c - 128;
      const float bv = bh[vcol];
#pragma unroll
      for (int m = 0; m < 4; ++m) {
        const int n0 = (row0 & 4095) + wr * 64 + m * 16 + h * 4;  // mult of 4
        const int tt = n0 >> 5, kvo = n0 & 31;
        const uint32_t dd = pk4fp8(acc[m][n][0] + bv, acc[m][n][1] + bv,
                                   acc[m][n][2] + bv, acc[m][n][3] + bv);
        *(uint32_t*)(V8 + (((size_t)(b * 128 + tt) * 512 + vcol) * 32 + kvo)) = dd;
      }
    }
  }
}

// ---------------------------------------------------------------------------
// Kernel 2: flash attention, EPOCH=128 kv, PV via MX-scaled fp8 16x16x128
// (unit scales).  32 epochs, 1 barrier each.  Waves 0-3 produce P(e+1):
// 16 bf16 QK MFMAs into sc[8] (both 64-kv halves), ONE combined max/ballot
// (both halves share m — required since one MX MFMA spans 128 kv), exp2-
// domain softmax, fp8 pack.  All 8 waves: 16 MX MFMA over own 64 V-cols.
// V-waves stage 2 K-tiles/epoch via gl16.  2 blocks/CU needs VGPR <= 64.
// ---------------------------------------------------------------------------
__global__ __launch_bounds__(512, 4) void kattn(const ushortT* __restrict__ Qg,
                                                const ushortT* __restrict__ Kg,
                                                const uint8_t* __restrict__ V8,
                                                const float* __restrict__ x,
                                                const float* __restrict__ gamma,
                                                float* __restrict__ out) {
  // P fp8: Pl[slot][(qi*64+lane)*8 + widx]; lane reads 32B (one MX A-frag)
  __shared__ __align__(16) uint32_t Pl[2][2048];          // 16KB
  __shared__ __align__(16) ushortT Klds[2][2][64 * 64];   // 32KB [slot][half]
  __shared__ __align__(16) float alpha_s[2][64];
  __shared__ __align__(16) int   flag_s[2][4];
  __shared__ __align__(16) float lsum_s[64];

  const int tid = threadIdx.x;
  const int w = tid >> 6, l = tid & 63, h = l >> 4, c = l & 15;
  const int bb = blockIdx.x & 7, qb = blockIdx.x >> 3;   // XCD-aware swizzle
  const size_t qrow0 = (size_t)bb * 4096 + (size_t)qb * 64;

  f4 acc[4][4];
#pragma unroll
  for (int qi = 0; qi < 4; ++qi)
#pragma unroll
    for (int vj = 0; vj < 4; ++vj) acc[qi][vj] = (f4){0.f, 0.f, 0.f, 0.f};

  const ushortT* Kb = Kg + (size_t)bb * 4096 * 64;
  const uint8_t* Vb = V8 + (size_t)bb * 512 * 4096;

  // V (fp8, MX B-frag): lane (c,h) reads 32B = V8[kvtile=4e+h][col][0..31]
  const uint8_t* vptr = Vb + (size_t)h * 16384 + (size_t)(w * 64 + c) * 32;
  // K staging source offset for stager waves w>=4 (pre-swizzled; w&3 quarter)
  const size_t koff = (size_t)((w & 3) * 16 + (l >> 3)) * 64 +
                      8 * ((l & 7) ^ (l >> 3));

  // Q fragments (B-operand of S^T): q = w*16 + c   (pre-scaled by log2e)
  s8v qf[2];
  if (w < 4) {
#pragma unroll
    for (int ks = 0; ks < 2; ++ks)
      qf[ks] = *(const s8v*)(Qg + (qrow0 + w * 16 + c) * 64 + ks * 32 + h * 8);
  }
  float m_run = -__builtin_inff();   // log2 domain
  float l_run = 0.0f;   // per-lane partial; combined across h at epilogue

  // softmax tail over a FULL 128-kv epoch: sc[T*4+j][r] = S2[kv=64T+16j+4h+r][q]
  auto softmax_store8 = [&](const f4* sc, int nb) {
    float tm = sc[0][0];
#pragma unroll
    for (int idx = 0; idx < 8; ++idx)
#pragma unroll
      for (int r = 0; r < 4; ++r) tm = fmaxf(tm, sc[idx][r]);
    // ballot-first defer-max; THR = 5.77 bits -> P <= 2^5.77 = 54.6 << 448
    const unsigned long long bal = __ballot(tm > m_run + 5.77f);
    float al = 1.0f;
    if (bal) {
      tm = fmaxf(tm, __shfl_xor(tm, 16));
      tm = fmaxf(tm, __shfl_xor(tm, 32));
      const float mn = fmaxf(m_run, tm);
      al = ex2(m_run - mn);   // 0 on first epoch
      m_run = mn;
    }
    float ps = 0.0f;
#pragma unroll
    for (int T = 0; T < 2; ++T)
#pragma unroll
      for (int j = 0; j < 4; ++j) {
        const int idx = T * 4 + j;
        const float p0 = ex2(sc[idx][0] - m_run), p1 = ex2(sc[idx][1] - m_run);
        const float p2 = ex2(sc[idx][2] - m_run), p3 = ex2(sc[idx][3] - m_run);
        ps += (p0 + p1) + (p2 + p3);
        // consumer A-frag: lane(c,hc) word widx byte b <-> kv = hc*32+widx*4+b
        // hc = 2T + (j>>1), widx = 4*(j&1) + h, b = r   (derived, bijective)
        const uint32_t pw = pk4fp8(p0, p1, p2, p3);
        Pl[nb][(w * 64 + c + 16 * (2 * T + (j >> 1))) * 8 + 4 * (j & 1) + h] = pw;
      }
    l_run = l_run * al + ps;
    if (bal && h == 0) alpha_s[nb][w * 16 + c] = al;
    if (l == 0) flag_s[nb][w] = bal ? 1 : 0;
  };

  // produce epoch's P from Klds[kb] (both 64-kv halves)
  auto produce_lds = [&](int kb, int nb) {
    f4 sc[8];
#pragma unroll
    for (int i = 0; i < 8; ++i) sc[i] = (f4){0.f, 0.f, 0.f, 0.f};
    __builtin_amdgcn_s_setprio(1);
#pragma unroll
    for (int T = 0; T < 2; ++T) {
      const char* kbp = (const char*)Klds[kb][T];
#pragma unroll
      for (int j = 0; j < 4; ++j)
#pragma unroll
        for (int ks = 0; ks < 2; ++ks) {
          s8v kf = *(const s8v*)(kbp + (size_t)(j * 16 + c) * 128 +
                                 (((ks * 4 + h) ^ (c & 7)) * 16));
          sc[T * 4 + j] = MFMA_BF16(kf, qf[ks], sc[T * 4 + j]);
        }
    }
    __builtin_amdgcn_s_setprio(0);
    softmax_store8(sc, nb);
  };

  // ---- prologue: S-waves produce epoch 0 from global K; V-waves stage ep 1
  if (w < 4) {
    f4 sc[8];
#pragma unroll
    for (int i = 0; i < 8; ++i) sc[i] = (f4){0.f, 0.f, 0.f, 0.f};
#pragma unroll
    for (int T = 0; T < 2; ++T)
#pragma unroll
      for (int j = 0; j < 4; ++j)
#pragma unroll
        for (int ks = 0; ks < 2; ++ks) {
          s8v kf = *(const s8v*)(Kb + (size_t)(T * 64 + j * 16 + c) * 64 +
                                 ks * 32 + h * 8);
          sc[T * 4 + j] = MFMA_BF16(kf, qf[ks], sc[T * 4 + j]);
        }
    softmax_store8(sc, 0);
  } else {
    const ushortT* ksrc = Kb + 8192 + koff;
    gl16(ksrc,              (char*)Klds[1][0] + (w & 3) * 2048);
    gl16(ksrc + 512,        (char*)Klds[1][0] + (w & 3) * 2048 + 1024);
    gl16(ksrc + 4096,       (char*)Klds[1][1] + (w & 3) * 2048);
    gl16(ksrc + 4096 + 512, (char*)Klds[1][1] + (w & 3) * 2048 + 1024);
  }
  asm volatile("s_waitcnt vmcnt(0) lgkmcnt(0)" ::: "memory");
  __builtin_amdgcn_s_barrier();

  for (int e = 0; e < 32; ++e) {
    const int cur = e & 1;
    // ---- P A-frags (32B each) + flag for epoch e
    i8v pa[4];
#pragma unroll
    for (int qi = 0; qi < 4; ++qi)
      pa[qi] = *(const i8v*)&Pl[cur][(qi * 64 + l) * 8];
    i4v fl = *(const i4v*)&flag_s[cur][0];
    // ---- stagers (V-waves): 2 K-tiles for epoch e+2 -> Klds[e&1]
    if (w >= 4 && e < 30) {
      const ushortT* ksrc = Kb + (size_t)(e + 2) * 8192 + koff;
      gl16(ksrc,              (char*)Klds[cur][0] + (w & 3) * 2048);
      gl16(ksrc + 512,        (char*)Klds[cur][0] + (w & 3) * 2048 + 1024);
      gl16(ksrc + 4096,       (char*)Klds[cur][1] + (w & 3) * 2048);
      gl16(ksrc + 4096 + 512, (char*)Klds[cur][1] + (w & 3) * 2048 + 1024);
    }
    // ---- deferred rescale (once per 128 kv now)
#pragma unroll
    for (int qi = 0; qi < 4; ++qi) {
      if (fl[qi]) {
        f4 a4 = *(const f4*)&alpha_s[cur][qi * 16 + h * 4];
#pragma unroll
        for (int vj = 0; vj < 4; ++vj)
#pragma unroll
          for (int r = 0; r < 4; ++r) acc[qi][vj][r] *= a4[r];
      }
    }
    // ---- PV: 4 quarters, each {1 V-load (32B), 4 MX MFMA}
#pragma unroll
    for (int vj = 0; vj < 4; ++vj) {
      const i8v vf = *(const i8v*)(vptr + vj * 512);
      __builtin_amdgcn_s_setprio(1);
#pragma unroll
      for (int qi = 0; qi < 4; ++qi)
        acc[qi][vj] = MFMA_MX(pa[qi], vf, acc[qi][vj]);
      __builtin_amdgcn_s_setprio(0);
    }
    vptr += 65536;
    // ---- S-waves: produce epoch e+1 from Klds[(e+1)&1]
    if (w < 4 && e < 31) produce_lds(cur ^ 1, cur ^ 1);
    if (e < 31) {
      asm volatile("s_waitcnt vmcnt(0) lgkmcnt(0)" ::: "memory");
      __builtin_amdgcn_s_barrier();
    }
  }

  // ---- finalize: combine per-lane l partials across h, then epilogue
  l_run += __shfl_xor(l_run, 16);
  l_run += __shfl_xor(l_run, 32);
  if (w < 4 && h == 0) lsum_s[w * 16 + c] = l_run;
  __syncthreads();
#pragma unroll
  for (int qi = 0; qi < 4; ++qi) {
    f4 l4 = *(const f4*)(&lsum_s[qi * 16 + h * 4]);
    f4 rl;
#pragma unroll
    for (int r = 0; r < 4; ++r) rl[r] = 1.0f / l4[r];
#pragma unroll
    for (int vj = 0; vj < 4; ++vj) {
      const int colg = w * 64 + vj * 16 + c;
      const float gm = gamma[colg];
#pragma unroll
      for (int r = 0; r < 4; ++r) {
        const size_t idx = (qrow0 + qi * 16 + h * 4 + r) * 512 + colg;
        out[idx] = gm * (acc[qi][vj][r] * rl[r]) + x[idx];
      }
    }
  }
}

// ---------------------------------------------------------------------------
extern "C" void kernel_launch(void* const* d_in, const int* in_sizes, int n_in,
                              void* d_out, int out_size, void* d_ws, size_t ws_size,
                              hipStream_t stream) {
  const float* x     = (const float*)d_in[0];
  const float* Wg    = (const float*)d_in[1];
  const float* bg    = (const float*)d_in[2];
  const float* Wf    = (const float*)d_in[3];
  const float* bfv   = (const float*)d_in[4];
  const float* Wh    = (const float*)d_in[5];
  const float* bh    = (const float*)d_in[6];
  const float* gamma = (const float*)d_in[7];
  float* out = (float*)d_out;
  char* ws = (char*)d_ws;

  // workspace: Q 4Mi | K 4Mi | V8 16Mi | Wt @40Mi (640KiB)
  // xb (bf16 x, 32MB) lives in d_out: kproj consumes it before kattn writes.
  ushortT* Q  = (ushortT*)(ws);
  ushortT* K  = (ushortT*)(ws + ((size_t)4 << 20));
  uint8_t* V8 = (uint8_t*)(ws + ((size_t)8 << 20));
  ushortT* Wt = (ushortT*)(ws + ((size_t)40 << 20));
  ushortT* xb = (ushortT*)d_out;

  kxcvt<<<dim3(2048), dim3(256), 0, stream>>>(x, xb);
  kprep<<<dim3(640), dim3(64), 0, stream>>>(Wg, Wf, Wh, Wt);
  kproj<<<dim3(5, 256), dim3(256), 0, stream>>>(xb, Wt, bg, bfv, bh, Q, K, V8);
  kattn<<<dim3(512), dim3(512), 0, stream>>>(Q, K, V8, x, gamma, out);
}

// Round 12
// 226.979 us; speedup vs baseline: 1.9247x; 1.9247x over previous
//
#include <hip/hip_runtime.h>
#include <stdint.h>

// ---------- types ----------
using s8v  = __attribute__((ext_vector_type(8))) short;    // 8 bf16 (A/B frag)
using f4   = __attribute__((ext_vector_type(4))) float;    // C/D frag
using u32x4 = __attribute__((ext_vector_type(4))) uint32_t;
using u32x2 = __attribute__((ext_vector_type(2))) uint32_t;
using vf4  = __attribute__((ext_vector_type(4))) float;
using i4v  = __attribute__((ext_vector_type(4))) int;

typedef unsigned short ushortT;

#define LOG2E 1.4426950408889634f

// bf16 round-to-nearest-even
static __device__ __forceinline__ uint32_t bfr16(float f) {
  union { float f; uint32_t u; } v; v.f = f;
  return (v.u + 0x7FFFu + ((v.u >> 16) & 1u)) >> 16;
}
static __device__ __forceinline__ uint32_t pk2(float lo, float hi) {
  return (bfr16(hi) << 16) | (bfr16(lo) & 0xFFFFu);
}
// pack 4 f32 -> 4 fp8 e4m3 bytes (saturating RNE)
static __device__ __forceinline__ uint32_t pk4fp8(float a, float b, float cc, float d) {
  int w = __builtin_amdgcn_cvt_pk_fp8_f32(a, b, 0, false);    // bytes 0,1
  w = __builtin_amdgcn_cvt_pk_fp8_f32(cc, d, w, true);        // bytes 2,3
  return (uint32_t)w;
}
// native 2^x (single v_exp_f32 — exp2f() is a slow libm call, R9 lesson)
static __device__ __forceinline__ float ex2(float x) {
#if __has_builtin(__builtin_amdgcn_exp2f)
  return __builtin_amdgcn_exp2f(x);
#else
  float r; asm("v_exp_f32 %0, %1" : "=v"(r) : "v"(x)); return r;
#endif
}
// async global->LDS, 16B per lane
static __device__ __forceinline__ void gl16(const void* g, void* l) {
  __builtin_amdgcn_global_load_lds((const __attribute__((address_space(1))) uint32_t*)g,
                                   (__attribute__((address_space(3))) uint32_t*)l, 16, 0, 0);
}

#define MFMA_BF16(A, B, C) __builtin_amdgcn_mfma_f32_16x16x32_bf16((A), (B), (C), 0, 0, 0)
#define MFMA_FP8(A, B, C)  __builtin_amdgcn_mfma_f32_16x16x32_fp8_fp8((A), (B), (C), 0, 0, 0)

// ---------------------------------------------------------------------------
// Kernel X: x fp32 -> xb bf16 (row-major), one pass.  xb lives in d_out
// (64MB >= 32MB; kproj consumes it before kattn overwrites d_out).
// ---------------------------------------------------------------------------
__global__ __launch_bounds__(256) void kxcvt(const float* __restrict__ x,
                                             ushortT* __restrict__ xb) {
  const size_t stride = (size_t)2048 * 256 * 8;
  size_t idx = ((size_t)blockIdx.x * 256 + threadIdx.x) * 8;
#pragma unroll
  for (int i = 0; i < 4; ++i) {
    vf4 a = *(const vf4*)(x + idx);
    vf4 b = *(const vf4*)(x + idx + 4);
    u32x4 o = { pk2(a[0], a[1]), pk2(a[2], a[3]),
                pk2(b[0], b[1]), pk2(b[2], b[3]) };
    *(u32x4*)(xb + idx) = o;
    idx += stride;
  }
}

// ---------------------------------------------------------------------------
// Kernel 0: weights -> bf16, transposed: Wt[640][512]
// ---------------------------------------------------------------------------
__global__ __launch_bounds__(64) void kprep(const float* __restrict__ Wg,
                                            const float* __restrict__ Wf,
                                            const float* __restrict__ Wh,
                                            ushortT* __restrict__ Wt) {
  const int cIdx = blockIdx.x;     // 0..639
  const int t = threadIdx.x;       // 64
  const float* src; int co, ldc;
  if (cIdx < 64)       { src = Wg; co = cIdx;       ldc = 64;  }
  else if (cIdx < 128) { src = Wf; co = cIdx - 64;  ldc = 64;  }
  else                 { src = Wh; co = cIdx - 128; ldc = 512; }
#pragma unroll
  for (int kk = 0; kk < 8; ++kk) {
    int k = kk * 64 + t;
    Wt[(size_t)cIdx * 512 + k] = (ushortT)bfr16(src[(size_t)k * ldc + co]);
  }
}

// ---------------------------------------------------------------------------
// Kernel 1: projection GEMM, 128x128 tile; BOTH operands gl16-staged from
// bf16 (A from xb — no fp32 re-read, no cvt VALU).
// ---------------------------------------------------------------------------
__global__ __launch_bounds__(256) void kproj(const ushortT* __restrict__ xb,
                                             const ushortT* __restrict__ Wt,
                                             const float* __restrict__ bg,
                                             const float* __restrict__ bfv,
                                             const float* __restrict__ bh,
                                             ushortT* __restrict__ Q,
                                             ushortT* __restrict__ K,
                                             uint8_t* __restrict__ V8) {
  __shared__ ushortT Al[128 * 64];   // 16KB [row][k], chunk16 ^= row&7
  __shared__ ushortT Bl[128 * 64];   // 16KB [col][k], chunk16 ^= col&7

  const int tid = threadIdx.x;
  const int w = tid >> 6, l = tid & 63, h = l >> 4, c = l & 15;
  const int wr = w >> 1, wc = w & 1;           // 2x2 wave grid
  const int ct = blockIdx.x, rt = blockIdx.y;
  const int row0 = rt * 128;

  f4 acc[4][4];
#pragma unroll
  for (int m = 0; m < 4; ++m)
#pragma unroll
    for (int n = 0; n < 4; ++n) acc[m][n] = (f4){0.f, 0.f, 0.f, 0.f};

  for (int kk = 0; kk < 8; ++kk) {
    const int k0 = kk * 64;
    // ---- stage A via gl16: 4 per thread (source pre-swizzled, dest linear)
#pragma unroll
    for (int i = 0; i < 4; ++i) {
      const int ch = i * 256 + tid;              // LDS 16B-chunk index
      const int row = ch >> 3, kc = ch & 7;
      const ushortT* src = xb + (size_t)(row0 + row) * 512 + k0 +
                           8 * (kc ^ (row & 7));
      gl16(src, (char*)Al + ch * 16);
    }
    // ---- stage B: 4 gl16 per wave (source pre-swizzled, dest linear)
#pragma unroll
    for (int i = 0; i < 4; ++i) {
      const int col = w * 32 + i * 8 + (l >> 3);
      const ushortT* src = Wt + (size_t)(ct * 128 + col) * 512 + k0 +
                           8 * ((l & 7) ^ (l >> 3));
      gl16(src, (char*)Bl + (w * 4 + i) * 1024);
    }
    __syncthreads();
    // ---- MFMA: wave (wr,wc) owns rows wr*64.., cols wc*64..
#pragma unroll
    for (int ks = 0; ks < 2; ++ks) {
      s8v a[4], b[4];
#pragma unroll
      for (int m = 0; m < 4; ++m)
        a[m] = *(const s8v*)((char*)Al + (size_t)(wr * 64 + m * 16 + c) * 128 +
                             (((ks * 4 + h) ^ (c & 7)) * 16));
#pragma unroll
      for (int n = 0; n < 4; ++n)
        b[n] = *(const s8v*)((char*)Bl + (size_t)(wc * 64 + n * 16 + c) * 128 +
                             (((ks * 4 + h) ^ (c & 7)) * 16));
#pragma unroll
      for (int m = 0; m < 4; ++m)
#pragma unroll
        for (int n = 0; n < 4; ++n)
          acc[m][n] = MFMA_BF16(a[m], b[n], acc[m][n]);
    }
    __syncthreads();
  }

  // ---- epilogue: route by global column
  if (ct == 0) {
    ushortT* dst = (wc == 0) ? Q : K;
    const float* bias = (wc == 0) ? bg : bfv;
    const float scl = (wc == 0) ? LOG2E : 1.0f;
#pragma unroll
    for (int n = 0; n < 4; ++n) {
      const int col = n * 16 + c;
      const float bv = bias[col];
#pragma unroll
      for (int m = 0; m < 4; ++m) {
        const int grow = row0 + wr * 64 + m * 16 + h * 4;
#pragma unroll
        for (int r = 0; r < 4; ++r)
          dst[(size_t)(grow + r) * 64 + col] = (ushortT)bfr16((acc[m][n][r] + bv) * scl);
      }
    }
  } else {
    const int b = row0 >> 12;
#pragma unroll
    for (int n = 0; n < 4; ++n) {
      const int vcol = ct * 128 + wc * 64 + n * 16 + c - 128;
      const float bv = bh[vcol];
#pragma unroll
      for (int m = 0; m < 4; ++m) {
        const int n0 = (row0 & 4095) + wr * 64 + m * 16 + h * 4;  // mult of 4
        const int tt = n0 >> 5, kvo = n0 & 31;
        const uint32_t dd = pk4fp8(acc[m][n][0] + bv, acc[m][n][1] + bv,
                                   acc[m][n][2] + bv, acc[m][n][3] + bv);
        *(uint32_t*)(V8 + (((size_t)(b * 128 + tt) * 512 + vcol) * 32 + kvo)) = dd;
      }
    }
  }
}

// ---------------------------------------------------------------------------
// Kernel 2: flash attention (R10 known-good).  KVBLK=64, fp8 P & V (e4m3,
// non-MX 16x16x32 — fits the 64-VGPR budget; MX K=128 spilled, R11 lesson),
// exp2-domain softmax with native v_exp_f32 (Q pre-scaled by log2e).
// Waves 0-3 produce P(t+1); V-waves (4-7) stage K tiles via gl16 and do PV.
// __launch_bounds__(512,4): 2 blocks/CU requires arch VGPR <= 64.
// ---------------------------------------------------------------------------
__global__ __launch_bounds__(512, 4) void kattn(const ushortT* __restrict__ Qg,
                                                const ushortT* __restrict__ Kg,
                                                const uint8_t* __restrict__ V8,
                                                const float* __restrict__ x,
                                                const float* __restrict__ gamma,
                                                float* __restrict__ out) {
  // P fp8 frag-major: Pl[slot][kslot][(qi*64 + lane)*2 + word]  (8 KB)
  __shared__ __align__(16) uint32_t Pl[2][2][512];
  __shared__ __align__(16) ushortT Klds[2][64 * 64];      // 16KB K tiles, dbuf
  __shared__ __align__(16) float alpha_s[2][64];
  __shared__ __align__(16) int   flag_s[2][4];
  __shared__ __align__(16) float lsum_s[64];

  const int tid = threadIdx.x;
  const int w = tid >> 6, l = tid & 63, h = l >> 4, c = l & 15;
  const int bb = blockIdx.x & 7, qb = blockIdx.x >> 3;   // XCD-aware swizzle
  const size_t qrow0 = (size_t)bb * 4096 + (size_t)qb * 64;

  f4 acc[4][4];
#pragma unroll
  for (int qi = 0; qi < 4; ++qi)
#pragma unroll
    for (int vj = 0; vj < 4; ++vj) acc[qi][vj] = (f4){0.f, 0.f, 0.f, 0.f};

  const ushortT* Kb = Kg + (size_t)bb * 4096 * 64;
  const uint8_t* Vb = V8 + (size_t)bb * 512 * 4096;

  // V source (fp8): 8B per lane; wave covers 512 contiguous bytes per load.
  const uint8_t* vptr = Vb + (size_t)(w * 64 + c) * 32 + h * 8;  // +32768 B/iter
  // K staging source offset for stager waves w>=4 (pre-swizzled; w&3 quarter)
  const size_t koff = (size_t)((w & 3) * 16 + (l >> 3)) * 64 +
                      8 * ((l & 7) ^ (l >> 3));

  // Q fragments (B-operand of S^T): q = w*16 + c   (pre-scaled by log2e)
  s8v qf[2];
  if (w < 4) {
#pragma unroll
    for (int ks = 0; ks < 2; ++ks)
      qf[ks] = *(const s8v*)(Qg + (qrow0 + w * 16 + c) * 64 + ks * 32 + h * 8);
  }
  float m_run = -__builtin_inff();   // log2 domain
  float l_run = 0.0f;   // per-lane partial; combined across h at epilogue

  // softmax tail (log2 domain): sc[j][r] = S2[kv=j*16+h*4+r][q=w*16+c]
  auto softmax_store = [&](const f4* sc, int nb) {
    float tm = fmaxf(fmaxf(fmaxf(sc[0][0], sc[0][1]), fmaxf(sc[0][2], sc[0][3])),
                     fmaxf(fmaxf(sc[1][0], sc[1][1]), fmaxf(sc[1][2], sc[1][3])));
    tm = fmaxf(tm, fmaxf(fmaxf(fmaxf(sc[2][0], sc[2][1]), fmaxf(sc[2][2], sc[2][3])),
                         fmaxf(fmaxf(sc[3][0], sc[3][1]), fmaxf(sc[3][2], sc[3][3]))));
    // ballot-first defer-max; THR = 4 nats = 5.77 bits -> P <= 2^5.77 = 54.6
    const unsigned long long bal = __ballot(tm > m_run + 5.77f);
    float al = 1.0f;
    if (bal) {
      tm = fmaxf(tm, __shfl_xor(tm, 16));
      tm = fmaxf(tm, __shfl_xor(tm, 32));
      const float mn = fmaxf(m_run, tm);
      al = ex2(m_run - mn);   // 0 on first tile
      m_run = mn;
    }
    float ps = 0.0f;
#pragma unroll
    for (int j = 0; j < 4; ++j) {
      const float p0 = ex2(sc[j][0] - m_run), p1 = ex2(sc[j][1] - m_run);
      const float p2 = ex2(sc[j][2] - m_run), p3 = ex2(sc[j][3] - m_run);
      ps += (p0 + p1) + (p2 + p3);
      // word = fp8{p0..p3} -> kv j*16+h*4+{0..3}; consumer lane/word mapping:
      // s = j>>1, h_c = 2*(j&1) + (h>>1), b = h&1
      const uint32_t pw = pk4fp8(p0, p1, p2, p3);
      const int s = j >> 1;
      const int hc = 2 * (j & 1) + (h >> 1);
      Pl[nb][s][(w * 64 + c + 16 * hc) * 2 + (h & 1)] = pw;
    }
    l_run = l_run * al + ps;
    if (bal && h == 0) alpha_s[nb][w * 16 + c] = al;
    if (l == 0) flag_s[nb][w] = bal ? 1 : 0;
  };

  // produce from Klds[kb]: S^T for kv-tile, then softmax+store
  auto produce_lds = [&](int kb, int nb) {
    f4 sc[4];
#pragma unroll
    for (int j = 0; j < 4; ++j) sc[j] = (f4){0.f, 0.f, 0.f, 0.f};
    const char* kbp = (const char*)Klds[kb];
    __builtin_amdgcn_s_setprio(1);
#pragma unroll
    for (int j = 0; j < 4; ++j) {
#pragma unroll
      for (int ks = 0; ks < 2; ++ks) {
        s8v kf = *(const s8v*)(kbp + (size_t)(j * 16 + c) * 128 +
                               (((ks * 4 + h) ^ (c & 7)) * 16));
        sc[j] = MFMA_BF16(kf, qf[ks], sc[j]);
      }
    }
    __builtin_amdgcn_s_setprio(0);
    softmax_store(sc, nb);
  };

  // ---- prologue: S-waves produce P(0) from global K; V-waves stage K(1)
  if (w < 4) {
    f4 sc[4];
#pragma unroll
    for (int j = 0; j < 4; ++j) sc[j] = (f4){0.f, 0.f, 0.f, 0.f};
#pragma unroll
    for (int j = 0; j < 4; ++j) {
#pragma unroll
      for (int ks = 0; ks < 2; ++ks) {
        s8v kf = *(const s8v*)(Kb + (size_t)(j * 16 + c) * 64 + ks * 32 + h * 8);
        sc[j] = MFMA_BF16(kf, qf[ks], sc[j]);
      }
    }
    softmax_store(sc, 0);
  } else {
    gl16(Kb + 4096 + koff, (char*)Klds[1] + (w & 3) * 2048);
    gl16(Kb + 4096 + koff + 512, (char*)Klds[1] + (w & 3) * 2048 + 1024);
  }
  asm volatile("s_waitcnt vmcnt(0) lgkmcnt(0)" ::: "memory");
  __builtin_amdgcn_s_barrier();

  for (int t = 0; t < 64; ++t) {
    const int cur = t & 1;
    // ---- P fragments (fp8, 8B each) + flags for tile t
    long paA[4], paB[4];
#pragma unroll
    for (int qi = 0; qi < 4; ++qi) {
      paA[qi] = *(const long*)&Pl[cur][0][(qi * 64 + l) * 2];
      paB[qi] = *(const long*)&Pl[cur][1][(qi * 64 + l) * 2];
    }
    i4v fl = *(const i4v*)&flag_s[cur][0];
    // ---- stagers (V-waves): K(t+2) -> Klds[t&1]
    if (w >= 4 && t < 62) {
      const ushortT* ks_src = Kb + (size_t)(t + 2) * 4096 + koff;
      gl16(ks_src, (char*)Klds[cur] + (w & 3) * 2048);
      gl16(ks_src + 512, (char*)Klds[cur] + (w & 3) * 2048 + 1024);
    }
    // ---- deferred rescale
#pragma unroll
    for (int qi = 0; qi < 4; ++qi) {
      if (fl[qi]) {
        f4 a4 = *(const f4*)&alpha_s[cur][qi * 16 + h * 4];
#pragma unroll
        for (int vj = 0; vj < 4; ++vj)
#pragma unroll
          for (int r = 0; r < 4; ++r) acc[qi][vj][r] *= a4[r];
      }
    }
    // ---- PV: 4 quarters, each {2 fp8 V-loads (8B), 8 fp8 MFMA}
#pragma unroll
    for (int vj = 0; vj < 4; ++vj) {
      const long vf0 = *(const long*)(vptr + vj * 512);
      const long vf1 = *(const long*)(vptr + 16384 + vj * 512);
      __builtin_amdgcn_s_setprio(1);
#pragma unroll
      for (int qi = 0; qi < 4; ++qi) {
        acc[qi][vj] = MFMA_FP8(paA[qi], vf0, acc[qi][vj]);
        acc[qi][vj] = MFMA_FP8(paB[qi], vf1, acc[qi][vj]);
      }
      __builtin_amdgcn_s_setprio(0);
    }
    vptr += 32768;
    // ---- S-waves: produce P(t+1) from Klds[(t+1)&1]
    if (t < 63) {
      if (w < 4) produce_lds(cur ^ 1, cur ^ 1);
      asm volatile("s_waitcnt vmcnt(0) lgkmcnt(0)" ::: "memory");
      __builtin_amdgcn_s_barrier();
    }
  }

  // ---- finalize: combine per-lane l partials across h, then epilogue
  l_run += __shfl_xor(l_run, 16);
  l_run += __shfl_xor(l_run, 32);
  if (w < 4 && h == 0) lsum_s[w * 16 + c] = l_run;
  __syncthreads();
#pragma unroll
  for (int qi = 0; qi < 4; ++qi) {
    f4 l4 = *(const f4*)(&lsum_s[qi * 16 + h * 4]);
    f4 rl;
#pragma unroll
    for (int r = 0; r < 4; ++r) rl[r] = 1.0f / l4[r];
#pragma unroll
    for (int vj = 0; vj < 4; ++vj) {
      const int colg = w * 64 + vj * 16 + c;
      const float gm = gamma[colg];
#pragma unroll
      for (int r = 0; r < 4; ++r) {
        const size_t idx = (qrow0 + qi * 16 + h * 4 + r) * 512 + colg;
        out[idx] = gm * (acc[qi][vj][r] * rl[r]) + x[idx];
      }
    }
  }
}

// ---------------------------------------------------------------------------
extern "C" void kernel_launch(void* const* d_in, const int* in_sizes, int n_in,
                              void* d_out, int out_size, void* d_ws, size_t ws_size,
                              hipStream_t stream) {
  const float* x     = (const float*)d_in[0];
  const float* Wg    = (const float*)d_in[1];
  const float* bg    = (const float*)d_in[2];
  const float* Wf    = (const float*)d_in[3];
  const float* bfv   = (const float*)d_in[4];
  const float* Wh    = (const float*)d_in[5];
  const float* bh    = (const float*)d_in[6];
  const float* gamma = (const float*)d_in[7];
  float* out = (float*)d_out;
  char* ws = (char*)d_ws;

  // workspace: Q 4Mi | K 4Mi | V8 16Mi | Wt @40Mi (640KiB)
  // xb (bf16 x, 32MB) lives in d_out: kproj consumes it before kattn writes.
  ushortT* Q  = (ushortT*)(ws);
  ushortT* K  = (ushortT*)(ws + ((size_t)4 << 20));
  uint8_t* V8 = (uint8_t*)(ws + ((size_t)8 << 20));
  ushortT* Wt = (ushortT*)(ws + ((size_t)40 << 20));
  ushortT* xb = (ushortT*)d_out;

  kxcvt<<<dim3(2048), dim3(256), 0, stream>>>(x, xb);
  kprep<<<dim3(640), dim3(64), 0, stream>>>(Wg, Wf, Wh, Wt);
  kproj<<<dim3(5, 256), dim3(256), 0, stream>>>(xb, Wt, bg, bfv, bh, Q, K, V8);
  kattn<<<dim3(512), dim3(512), 0, stream>>>(Q, K, V8, x, gamma, out);
}

// Round 13
// 223.865 us; speedup vs baseline: 1.9515x; 1.0139x over previous
//
#include <hip/hip_runtime.h>
#include <stdint.h>

// ---------- types ----------
using s8v  = __attribute__((ext_vector_type(8))) short;    // 8 bf16 (A/B frag)
using f4   = __attribute__((ext_vector_type(4))) float;    // C/D frag
using u32x4 = __attribute__((ext_vector_type(4))) uint32_t;
using u32x2 = __attribute__((ext_vector_type(2))) uint32_t;
using vf4  = __attribute__((ext_vector_type(4))) float;
using i4v  = __attribute__((ext_vector_type(4))) int;

typedef unsigned short ushortT;

#define LOG2E 1.4426950408889634f

// bf16 round-to-nearest-even
static __device__ __forceinline__ uint32_t bfr16(float f) {
  union { float f; uint32_t u; } v; v.f = f;
  return (v.u + 0x7FFFu + ((v.u >> 16) & 1u)) >> 16;
}
static __device__ __forceinline__ uint32_t pk2(float lo, float hi) {
  return (bfr16(hi) << 16) | (bfr16(lo) & 0xFFFFu);
}
// pack 4 f32 -> 4 fp8 e4m3 bytes (saturating RNE)
static __device__ __forceinline__ uint32_t pk4fp8(float a, float b, float cc, float d) {
  int w = __builtin_amdgcn_cvt_pk_fp8_f32(a, b, 0, false);    // bytes 0,1
  w = __builtin_amdgcn_cvt_pk_fp8_f32(cc, d, w, true);        // bytes 2,3
  return (uint32_t)w;
}
// native 2^x (single v_exp_f32 — exp2f() is a slow libm call, R9 lesson)
static __device__ __forceinline__ float ex2(float x) {
#if __has_builtin(__builtin_amdgcn_exp2f)
  return __builtin_amdgcn_exp2f(x);
#else
  float r; asm("v_exp_f32 %0, %1" : "=v"(r) : "v"(x)); return r;
#endif
}
// async global->LDS, 16B per lane
static __device__ __forceinline__ void gl16(const void* g, void* l) {
  __builtin_amdgcn_global_load_lds((const __attribute__((address_space(1))) uint32_t*)g,
                                   (__attribute__((address_space(3))) uint32_t*)l, 16, 0, 0);
}

#define MFMA_BF16(A, B, C) __builtin_amdgcn_mfma_f32_16x16x32_bf16((A), (B), (C), 0, 0, 0)
#define MFMA_FP8(A, B, C)  __builtin_amdgcn_mfma_f32_16x16x32_fp8_fp8((A), (B), (C), 0, 0, 0)

// ---------------------------------------------------------------------------
// Kernel X: x fp32 -> xb bf16 (row-major), one pass.  xb lives in d_out
// (64MB >= 32MB; kproj consumes it before kattn overwrites d_out).
// ---------------------------------------------------------------------------
__global__ __launch_bounds__(256) void kxcvt(const float* __restrict__ x,
                                             ushortT* __restrict__ xb) {
  const size_t stride = (size_t)2048 * 256 * 8;
  size_t idx = ((size_t)blockIdx.x * 256 + threadIdx.x) * 8;
#pragma unroll
  for (int i = 0; i < 4; ++i) {
    vf4 a = *(const vf4*)(x + idx);
    vf4 b = *(const vf4*)(x + idx + 4);
    u32x4 o = { pk2(a[0], a[1]), pk2(a[2], a[3]),
                pk2(b[0], b[1]), pk2(b[2], b[3]) };
    *(u32x4*)(xb + idx) = o;
    idx += stride;
  }
}

// ---------------------------------------------------------------------------
// Kernel 0: weights -> bf16, transposed: Wt[640][512]
// ---------------------------------------------------------------------------
__global__ __launch_bounds__(64) void kprep(const float* __restrict__ Wg,
                                            const float* __restrict__ Wf,
                                            const float* __restrict__ Wh,
                                            ushortT* __restrict__ Wt) {
  const int cIdx = blockIdx.x;     // 0..639
  const int t = threadIdx.x;       // 64
  const float* src; int co, ldc;
  if (cIdx < 64)       { src = Wg; co = cIdx;       ldc = 64;  }
  else if (cIdx < 128) { src = Wf; co = cIdx - 64;  ldc = 64;  }
  else                 { src = Wh; co = cIdx - 128; ldc = 512; }
#pragma unroll
  for (int kk = 0; kk < 8; ++kk) {
    int k = kk * 64 + t;
    Wt[(size_t)cIdx * 512 + k] = (ushortT)bfr16(src[(size_t)k * ldc + co]);
  }
}

// ---------------------------------------------------------------------------
// Kernel 1: projection GEMM, 128x128 tile; BOTH operands gl16-staged from
// bf16 (A from xb — no fp32 re-read, no cvt VALU).
// ---------------------------------------------------------------------------
__global__ __launch_bounds__(256) void kproj(const ushortT* __restrict__ xb,
                                             const ushortT* __restrict__ Wt,
                                             const float* __restrict__ bg,
                                             const float* __restrict__ bfv,
                                             const float* __restrict__ bh,
                                             ushortT* __restrict__ Q,
                                             ushortT* __restrict__ K,
                                             uint8_t* __restrict__ V8) {
  __shared__ ushortT Al[128 * 64];   // 16KB [row][k], chunk16 ^= row&7
  __shared__ ushortT Bl[128 * 64];   // 16KB [col][k], chunk16 ^= col&7

  const int tid = threadIdx.x;
  const int w = tid >> 6, l = tid & 63, h = l >> 4, c = l & 15;
  const int wr = w >> 1, wc = w & 1;           // 2x2 wave grid
  const int ct = blockIdx.x, rt = blockIdx.y;
  const int row0 = rt * 128;

  f4 acc[4][4];
#pragma unroll
  for (int m = 0; m < 4; ++m)
#pragma unroll
    for (int n = 0; n < 4; ++n) acc[m][n] = (f4){0.f, 0.f, 0.f, 0.f};

  for (int kk = 0; kk < 8; ++kk) {
    const int k0 = kk * 64;
    // ---- stage A via gl16: 4 per thread (source pre-swizzled, dest linear)
#pragma unroll
    for (int i = 0; i < 4; ++i) {
      const int ch = i * 256 + tid;              // LDS 16B-chunk index
      const int row = ch >> 3, kc = ch & 7;
      const ushortT* src = xb + (size_t)(row0 + row) * 512 + k0 +
                           8 * (kc ^ (row & 7));
      gl16(src, (char*)Al + ch * 16);
    }
    // ---- stage B: 4 gl16 per wave (source pre-swizzled, dest linear)
#pragma unroll
    for (int i = 0; i < 4; ++i) {
      const int col = w * 32 + i * 8 + (l >> 3);
      const ushortT* src = Wt + (size_t)(ct * 128 + col) * 512 + k0 +
                           8 * ((l & 7) ^ (l >> 3));
      gl16(src, (char*)Bl + (w * 4 + i) * 1024);
    }
    __syncthreads();
    // ---- MFMA: wave (wr,wc) owns rows wr*64.., cols wc*64..
#pragma unroll
    for (int ks = 0; ks < 2; ++ks) {
      s8v a[4], b[4];
#pragma unroll
      for (int m = 0; m < 4; ++m)
        a[m] = *(const s8v*)((char*)Al + (size_t)(wr * 64 + m * 16 + c) * 128 +
                             (((ks * 4 + h) ^ (c & 7)) * 16));
#pragma unroll
      for (int n = 0; n < 4; ++n)
        b[n] = *(const s8v*)((char*)Bl + (size_t)(wc * 64 + n * 16 + c) * 128 +
                             (((ks * 4 + h) ^ (c & 7)) * 16));
#pragma unroll
      for (int m = 0; m < 4; ++m)
#pragma unroll
        for (int n = 0; n < 4; ++n)
          acc[m][n] = MFMA_BF16(a[m], b[n], acc[m][n]);
    }
    __syncthreads();
  }

  // ---- epilogue: route by global column
  if (ct == 0) {
    ushortT* dst = (wc == 0) ? Q : K;
    const float* bias = (wc == 0) ? bg : bfv;
    const float scl = (wc == 0) ? LOG2E : 1.0f;
#pragma unroll
    for (int n = 0; n < 4; ++n) {
      const int col = n * 16 + c;
      const float bv = bias[col];
#pragma unroll
      for (int m = 0; m < 4; ++m) {
        const int grow = row0 + wr * 64 + m * 16 + h * 4;
#pragma unroll
        for (int r = 0; r < 4; ++r)
          dst[(size_t)(grow + r) * 64 + col] = (ushortT)bfr16((acc[m][n][r] + bv) * scl);
      }
    }
  } else {
    const int b = row0 >> 12;
#pragma unroll
    for (int n = 0; n < 4; ++n) {
      const int vcol = ct * 128 + wc * 64 + n * 16 + c - 128;
      const float bv = bh[vcol];
#pragma unroll
      for (int m = 0; m < 4; ++m) {
        const int n0 = (row0 & 4095) + wr * 64 + m * 16 + h * 4;  // mult of 4
        const int tt = n0 >> 5, kvo = n0 & 31;
        const uint32_t dd = pk4fp8(acc[m][n][0] + bv, acc[m][n][1] + bv,
                                   acc[m][n][2] + bv, acc[m][n][3] + bv);
        *(uint32_t*)(V8 + (((size_t)(b * 128 + tt) * 512 + vcol) * 32 + kvo)) = dd;
      }
    }
  }
}

// ---------------------------------------------------------------------------
// Kernel 2: flash attention, KVBLK=64, fp8 P & V, PRODUCE-2-AHEAD pipeline:
// at iter t the S-wave runs PV(t) then produce(t+2) — the serial softmax
// tail has a full extra iteration before its consumer barrier.  Same wave
// produces every tile of its q-block (m stays in registers — R6 lesson).
// P/alpha/flag 4-slot; Klds 4-deep (V-waves stage K(t+4) into slot t&3,
// last read 2 barriers prior — race-free).  VGPR budget unchanged (<= 64).
// ---------------------------------------------------------------------------
__global__ __launch_bounds__(512, 4) void kattn(const ushortT* __restrict__ Qg,
                                                const ushortT* __restrict__ Kg,
                                                const uint8_t* __restrict__ V8,
                                                const float* __restrict__ x,
                                                const float* __restrict__ gamma,
                                                float* __restrict__ out) {
  // P fp8 frag-major: Pl[slot][kslot][(qi*64 + lane)*2 + word]  (16 KB)
  __shared__ __align__(16) uint32_t Pl[4][2][512];
  __shared__ __align__(16) ushortT Klds[4][64 * 64];      // 32KB K tiles, 4-deep
  __shared__ __align__(16) float alpha_s[4][64];
  __shared__ __align__(16) int   flag_s[4][4];
  __shared__ __align__(16) float lsum_s[64];

  const int tid = threadIdx.x;
  const int w = tid >> 6, l = tid & 63, h = l >> 4, c = l & 15;
  const int bb = blockIdx.x & 7, qb = blockIdx.x >> 3;   // XCD-aware swizzle
  const size_t qrow0 = (size_t)bb * 4096 + (size_t)qb * 64;

  f4 acc[4][4];
#pragma unroll
  for (int qi = 0; qi < 4; ++qi)
#pragma unroll
    for (int vj = 0; vj < 4; ++vj) acc[qi][vj] = (f4){0.f, 0.f, 0.f, 0.f};

  const ushortT* Kb = Kg + (size_t)bb * 4096 * 64;
  const uint8_t* Vb = V8 + (size_t)bb * 512 * 4096;

  // V source (fp8): 8B per lane; wave covers 512 contiguous bytes per load.
  const uint8_t* vptr = Vb + (size_t)(w * 64 + c) * 32 + h * 8;  // +32768 B/iter
  // K staging source offset for stager waves w>=4 (pre-swizzled; w&3 quarter)
  const size_t koff = (size_t)((w & 3) * 16 + (l >> 3)) * 64 +
                      8 * ((l & 7) ^ (l >> 3));

  // Q fragments (B-operand of S^T): q = w*16 + c   (pre-scaled by log2e)
  s8v qf[2];
  if (w < 4) {
#pragma unroll
    for (int ks = 0; ks < 2; ++ks)
      qf[ks] = *(const s8v*)(Qg + (qrow0 + w * 16 + c) * 64 + ks * 32 + h * 8);
  }
  float m_run = -__builtin_inff();   // log2 domain
  float l_run = 0.0f;   // per-lane partial; combined across h at epilogue

  // softmax tail (log2 domain): sc[j][r] = S2[kv=j*16+h*4+r][q=w*16+c]
  auto softmax_store = [&](const f4* sc, int nb) {
    float tm = fmaxf(fmaxf(fmaxf(sc[0][0], sc[0][1]), fmaxf(sc[0][2], sc[0][3])),
                     fmaxf(fmaxf(sc[1][0], sc[1][1]), fmaxf(sc[1][2], sc[1][3])));
    tm = fmaxf(tm, fmaxf(fmaxf(fmaxf(sc[2][0], sc[2][1]), fmaxf(sc[2][2], sc[2][3])),
                         fmaxf(fmaxf(sc[3][0], sc[3][1]), fmaxf(sc[3][2], sc[3][3]))));
    // ballot-first defer-max; THR = 4 nats = 5.77 bits -> P <= 2^5.77 = 54.6
    const unsigned long long bal = __ballot(tm > m_run + 5.77f);
    float al = 1.0f;
    if (bal) {
      tm = fmaxf(tm, __shfl_xor(tm, 16));
      tm = fmaxf(tm, __shfl_xor(tm, 32));
      const float mn = fmaxf(m_run, tm);
      al = ex2(m_run - mn);   // 0 on first tile
      m_run = mn;
    }
    float ps = 0.0f;
#pragma unroll
    for (int j = 0; j < 4; ++j) {
      const float p0 = ex2(sc[j][0] - m_run), p1 = ex2(sc[j][1] - m_run);
      const float p2 = ex2(sc[j][2] - m_run), p3 = ex2(sc[j][3] - m_run);
      ps += (p0 + p1) + (p2 + p3);
      // word = fp8{p0..p3} -> kv j*16+h*4+{0..3}; consumer lane/word mapping:
      // s = j>>1, h_c = 2*(j&1) + (h>>1), b = h&1
      const uint32_t pw = pk4fp8(p0, p1, p2, p3);
      const int s = j >> 1;
      const int hc = 2 * (j & 1) + (h >> 1);
      Pl[nb][s][(w * 64 + c + 16 * hc) * 2 + (h & 1)] = pw;
    }
    l_run = l_run * al + ps;
    if (bal && h == 0) alpha_s[nb][w * 16 + c] = al;
    if (l == 0) flag_s[nb][w] = bal ? 1 : 0;
  };

  // produce from Klds[kb]: S^T for kv-tile, then softmax+store
  auto produce_lds = [&](int kb, int nb) {
    f4 sc[4];
#pragma unroll
    for (int j = 0; j < 4; ++j) sc[j] = (f4){0.f, 0.f, 0.f, 0.f};
    const char* kbp = (const char*)Klds[kb];
    __builtin_amdgcn_s_setprio(1);
#pragma unroll
    for (int j = 0; j < 4; ++j) {
#pragma unroll
      for (int ks = 0; ks < 2; ++ks) {
        s8v kf = *(const s8v*)(kbp + (size_t)(j * 16 + c) * 128 +
                               (((ks * 4 + h) ^ (c & 7)) * 16));
        sc[j] = MFMA_BF16(kf, qf[ks], sc[j]);
      }
    }
    __builtin_amdgcn_s_setprio(0);
    softmax_store(sc, nb);
  };

  // ---- prologue: S-waves produce P(0), P(1) from global K;
  //      V-waves stage K(2) -> Klds[2], K(3) -> Klds[3]
  if (w < 4) {
#pragma unroll
    for (int t0 = 0; t0 < 2; ++t0) {
      f4 sc[4];
#pragma unroll
      for (int j = 0; j < 4; ++j) sc[j] = (f4){0.f, 0.f, 0.f, 0.f};
#pragma unroll
      for (int j = 0; j < 4; ++j) {
#pragma unroll
        for (int ks = 0; ks < 2; ++ks) {
          s8v kf = *(const s8v*)(Kb + (size_t)(t0 * 64 + j * 16 + c) * 64 +
                                 ks * 32 + h * 8);
          sc[j] = MFMA_BF16(kf, qf[ks], sc[j]);
        }
      }
      softmax_store(sc, t0);
    }
  } else {
#pragma unroll
    for (int tt = 2; tt < 4; ++tt) {
      const ushortT* ks_src = Kb + (size_t)tt * 4096 + koff;
      gl16(ks_src, (char*)Klds[tt] + (w & 3) * 2048);
      gl16(ks_src + 512, (char*)Klds[tt] + (w & 3) * 2048 + 1024);
    }
  }
  asm volatile("s_waitcnt vmcnt(0) lgkmcnt(0)" ::: "memory");
  __builtin_amdgcn_s_barrier();

  for (int t = 0; t < 64; ++t) {
    const int cur = t & 3;
    // ---- P fragments (fp8, 8B each) + flags for tile t (written at t-2)
    long paA[4], paB[4];
#pragma unroll
    for (int qi = 0; qi < 4; ++qi) {
      paA[qi] = *(const long*)&Pl[cur][0][(qi * 64 + l) * 2];
      paB[qi] = *(const long*)&Pl[cur][1][(qi * 64 + l) * 2];
    }
    i4v fl = *(const i4v*)&flag_s[cur][0];
    // ---- stagers (V-waves): K(t+4) -> Klds[t&3] (slot last read at t-2)
    if (w >= 4 && t < 60) {
      const ushortT* ks_src = Kb + (size_t)(t + 4) * 4096 + koff;
      gl16(ks_src, (char*)Klds[cur] + (w & 3) * 2048);
      gl16(ks_src + 512, (char*)Klds[cur] + (w & 3) * 2048 + 1024);
    }
    // ---- deferred rescale
#pragma unroll
    for (int qi = 0; qi < 4; ++qi) {
      if (fl[qi]) {
        f4 a4 = *(const f4*)&alpha_s[cur][qi * 16 + h * 4];
#pragma unroll
        for (int vj = 0; vj < 4; ++vj)
#pragma unroll
          for (int r = 0; r < 4; ++r) acc[qi][vj][r] *= a4[r];
      }
    }
    // ---- PV: 4 quarters, each {2 fp8 V-loads (8B), 8 fp8 MFMA}
#pragma unroll
    for (int vj = 0; vj < 4; ++vj) {
      const long vf0 = *(const long*)(vptr + vj * 512);
      const long vf1 = *(const long*)(vptr + 16384 + vj * 512);
      __builtin_amdgcn_s_setprio(1);
#pragma unroll
      for (int qi = 0; qi < 4; ++qi) {
        acc[qi][vj] = MFMA_FP8(paA[qi], vf0, acc[qi][vj]);
        acc[qi][vj] = MFMA_FP8(paB[qi], vf1, acc[qi][vj]);
      }
      __builtin_amdgcn_s_setprio(0);
    }
    vptr += 32768;
    // ---- S-waves: produce P(t+2) from Klds[(t+2)&3] (tail has 2-iter slack)
    if (w < 4 && t < 62) produce_lds((t + 2) & 3, (t + 2) & 3);
    if (t < 63) {
      asm volatile("s_waitcnt vmcnt(0) lgkmcnt(0)" ::: "memory");
      __builtin_amdgcn_s_barrier();
    }
  }

  // ---- finalize: combine per-lane l partials across h, then epilogue
  l_run += __shfl_xor(l_run, 16);
  l_run += __shfl_xor(l_run, 32);
  if (w < 4 && h == 0) lsum_s[w * 16 + c] = l_run;
  __syncthreads();
#pragma unroll
  for (int qi = 0; qi < 4; ++qi) {
    f4 l4 = *(const f4*)(&lsum_s[qi * 16 + h * 4]);
    f4 rl;
#pragma unroll
    for (int r = 0; r < 4; ++r) rl[r] = 1.0f / l4[r];
#pragma unroll
    for (int vj = 0; vj < 4; ++vj) {
      const int colg = w * 64 + vj * 16 + c;
      const float gm = gamma[colg];
#pragma unroll
      for (int r = 0; r < 4; ++r) {
        const size_t idx = (qrow0 + qi * 16 + h * 4 + r) * 512 + colg;
        out[idx] = gm * (acc[qi][vj][r] * rl[r]) + x[idx];
      }
    }
  }
}

// ---------------------------------------------------------------------------
extern "C" void kernel_launch(void* const* d_in, const int* in_sizes, int n_in,
                              void* d_out, int out_size, void* d_ws, size_t ws_size,
                              hipStream_t stream) {
  const float* x     = (const float*)d_in[0];
  const float* Wg    = (const float*)d_in[1];
  const float* bg    = (const float*)d_in[2];
  const float* Wf    = (const float*)d_in[3];
  const float* bfv   = (const float*)d_in[4];
  const float* Wh    = (const float*)d_in[5];
  const float* bh    = (const float*)d_in[6];
  const float* gamma = (const float*)d_in[7];
  float* out = (float*)d_out;
  char* ws = (char*)d_ws;

  // workspace: Q 4Mi | K 4Mi | V8 16Mi | Wt @40Mi (640KiB)
  // xb (bf16 x, 32MB) lives in d_out: kproj consumes it before kattn writes.
  ushortT* Q  = (ushortT*)(ws);
  ushortT* K  = (ushortT*)(ws + ((size_t)4 << 20));
  uint8_t* V8 = (uint8_t*)(ws + ((size_t)8 << 20));
  ushortT* Wt = (ushortT*)(ws + ((size_t)40 << 20));
  ushortT* xb = (ushortT*)d_out;

  kxcvt<<<dim3(2048), dim3(256), 0, stream>>>(x, xb);
  kprep<<<dim3(640), dim3(64), 0, stream>>>(Wg, Wf, Wh, Wt);
  kproj<<<dim3(5, 256), dim3(256), 0, stream>>>(xb, Wt, bg, bfv, bh, Q, K, V8);
  kattn<<<dim3(512), dim3(512), 0, stream>>>(Q, K, V8, x, gamma, out);
}